// Round 8
// baseline (431.649 us; speedup 1.0000x reference)
//
#include <hip/hip_runtime.h>
#include <math.h>

typedef __bf16 bf16;
typedef __bf16 bf16x8 __attribute__((ext_vector_type(8)));
typedef __bf16 bf16x4 __attribute__((ext_vector_type(4)));
typedef float f32x4 __attribute__((ext_vector_type(4)));

constexpr int cB = 256, cN = 256, cF = 128, cO = 256;
constexpr int BN = cB * cN;
constexpr float D2_FLOOR = 1e-12f;
constexpr float EPS_F = 1.401298464324817e-45f;  // np.spacing(float32(0))

// ---------------- workspace byte offsets ----------------
constexpr size_t OFF_LB = 0;                                  // bf16 [B][256][256]
constexpr size_t OFF_WT = OFF_LB + (size_t)cB * cN * cN * 2;  // bf16 [256][512]
constexpr size_t OFF_MT = OFF_WT + 512 * 256 * 2;             // bf16 [128][128]

// Direct global->VGPR MFMA fragment load: p = base of 16-row granule, ld in elems.
// lane l: row (l&15), k-slots k0 + 8*(l>>4) .. +7.
__device__ __forceinline__ bf16x8 gfrag(const bf16* __restrict__ p, int ld,
                                        int lane, int k0) {
  return *(const bf16x8*)(p + (size_t)(lane & 15) * ld + k0 + 8 * (lane >> 4));
}

// LDS MFMA fragment load from a [row][256B] buffer swizzled byte^=((row&7)<<4).
__device__ __forceinline__ bf16x8 lfragB(const char* base, int row0, int k0, int lane) {
  int row = row0 + (lane & 15);
  return *(const bf16x8*)(base + row * 256 +
                          ((2 * (k0 + 8 * (lane >> 4))) ^ ((row & 7) << 4)));
}

__device__ __forceinline__ f32x4 mfma(bf16x8 a, bf16x8 b, f32x4 c) {
  return __builtin_amdgcn_mfma_f32_16x16x32_bf16(a, b, c, 0, 0, 0);
}

// ---------------- k_wt: Wt[o][k*128+f]=weight[f*4+k][o]; MT[g][f]=M_L[f][g] --------
__global__ __launch_bounds__(256) void k_wt(const float* __restrict__ wgt,
                                            const float* __restrict__ ML,
                                            bf16* __restrict__ Wt,
                                            bf16* __restrict__ MT) {
  int id = blockIdx.x * 256 + threadIdx.x;
  if (id < 512 * 256) {
    int o = id >> 9, d = id & 511;
    int k = d >> 7, f = d & 127;
    Wt[id] = (bf16)wgt[(f * 4 + k) * 256 + o];
  } else {
    int id2 = id - 512 * 256;
    if (id2 < 128 * 128) {
      int g = id2 >> 7, f = id2 & 127;
      MT[id2] = (bf16)ML[f * 128 + g];
    }
  }
}

// ---------------- cheb_pass: one Chebyshev step (r7-proven) ----------------
// States in [f][i] LDS, row 512B, byte ^= ((f&7)<<4).  L from global (L2-warm).
__device__ __forceinline__ void cheb_pass(const bf16* __restrict__ Lm,
                                          const char* Bsrc, const char* Ppp,
                                          char* Odst, int wid, int lane, bool haspp) {
  int hi = lane >> 4, il = lane & 15;
  int i0w = wid * 32;
  f32x4 acc[2][8] = {};
#pragma unroll
  for (int ks = 0; ks < 8; ++ks) {
    int k0 = ks * 32;
    bf16x8 a0 = gfrag(Lm + (size_t)i0w * cN, cN, lane, k0);
    bf16x8 a1 = gfrag(Lm + (size_t)(i0w + 16) * cN, cN, lane, k0);
#pragma unroll
    for (int nf = 0; nf < 8; ++nf) {
      int f = nf * 16 + il;
      const char* p = Bsrc + f * 512 + ((64 * ks + 16 * hi) ^ ((il & 7) << 4));
      bf16x8 bb = *(const bf16x8*)p;
      acc[0][nf] = mfma(a0, bb, acc[0][nf]);
      acc[1][nf] = mfma(a1, bb, acc[1][nf]);
    }
  }
#pragma unroll
  for (int mf = 0; mf < 2; ++mf) {
    int ib = i0w + mf * 16 + 4 * hi;
#pragma unroll
    for (int nf = 0; nf < 8; ++nf) {
      int f = nf * 16 + il;
      int cb = (2 * ib) ^ ((il & 7) << 4);
      bf16x4 o;
      if (haspp) {
        bf16x4 pp = *(const bf16x4*)(Ppp + f * 512 + cb);
#pragma unroll
        for (int r = 0; r < 4; ++r) o[r] = (bf16)(2.f * acc[mf][nf][r] - (float)pp[r]);
      } else {
#pragma unroll
        for (int r = 0; r < 4; ++r) o[r] = (bf16)acc[mf][nf][r];
      }
      *(bf16x4*)(Odst + f * 512 + cb) = o;
    }
  }
}

// ---------------- k_mega: the whole per-mol pipeline in one block ----------------
__global__ __launch_bounds__(512, 1) void k_mega(const float* __restrict__ x,
                                                 const float* __restrict__ lap,
                                                 const int* __restrict__ na_p,
                                                 const bf16* __restrict__ MT,
                                                 const bf16* __restrict__ Wt,
                                                 const float* __restrict__ bias,
                                                 bf16* __restrict__ Lb,
                                                 float* __restrict__ out,
                                                 float* __restrict__ llearn) {
  __shared__ __align__(16) char bufA[65536];  // x^T / states [f][i], 512B rows, swz f
  __shared__ __align__(16) char bufB[65536];  // x / xw [n][*], 256B rows, swz n
  __shared__ float lsq[256];
  __shared__ float dinvl[256];
  int b = blockIdx.x;
  int tid = threadIdx.x, wid = tid >> 6, lane = tid & 63;
  int hi = lane >> 4, il = lane & 15;
  int na = na_p[b];
  const float* xb = x + (size_t)b * cN * cF;

  // ---- phase 1a: x (f32, masked) -> bufB [n][f] bf16 swizzled ----
#pragma unroll
  for (int it = 0; it < 16; ++it) {
    int e = (tid + it * 512) * 4;
    int n = e >> 7, f0 = e & 127;
    float m = (n < na) ? 1.f : 0.f;
    float4 v = *(const float4*)(xb + e);
    bf16x4 pk = {(bf16)(v.x * m), (bf16)(v.y * m), (bf16)(v.z * m), (bf16)(v.w * m)};
    *(bf16x4*)(bufB + n * 256 + ((2 * f0) ^ ((n & 7) << 4))) = pk;
  }
  __syncthreads();

  // ---- phase 1b: transpose bufB -> bufA [f][i] ----
#pragma unroll
  for (int it = 0; it < 16; ++it) {
    int u = tid + it * 512;
    int f = u & 127, i0 = 4 * (u >> 7);
    bf16x4 pk;
#pragma unroll
    for (int r = 0; r < 4; ++r) {
      int n = i0 + r;
      pk[r] = *(const bf16*)(bufB + n * 256 + ((2 * f) ^ ((n & 7) << 4)));
    }
    *(bf16x4*)(bufA + f * 512 + ((2 * i0) ^ ((f & 7) << 4))) = pk;
  }
  __syncthreads();

  // ---- phase 2: xw = x @ M_L (in-LDS, own rows), lsq = row sumsq ----
  {
    f32x4 acc[2][8] = {};
#pragma unroll
    for (int ks = 0; ks < 4; ++ks) {
      int k0 = ks * 32;
      bf16x8 a0 = lfragB(bufB, 32 * wid, k0, lane);
      bf16x8 a1 = lfragB(bufB, 32 * wid + 16, k0, lane);
#pragma unroll
      for (int gt = 0; gt < 8; ++gt) {
        bf16x8 bb = gfrag(MT + (size_t)gt * 16 * 128, 128, lane, k0);
        acc[0][gt] = mfma(a0, bb, acc[0][gt]);
        acc[1][gt] = mfma(a1, bb, acc[1][gt]);
      }
    }
#pragma unroll
    for (int nt = 0; nt < 2; ++nt) {
#pragma unroll
      for (int r = 0; r < 4; ++r) {
        int n = 32 * wid + 16 * nt + 4 * hi + r;
        int swz = (n & 7) << 4;
        float s = 0.f;
#pragma unroll
        for (int gt = 0; gt < 8; ++gt) {
          bf16 v = (bf16)acc[nt][gt][r];
          *(bf16*)(bufB + n * 256 + ((2 * (16 * gt + il)) ^ swz)) = v;
          float f = (float)v;
          s = fmaf(f, f, s);
        }
        s += __shfl_xor(s, 1); s += __shfl_xor(s, 2);
        s += __shfl_xor(s, 4); s += __shfl_xor(s, 8);
        if (il == 0) lsq[n] = s;
      }
    }
  }
  __syncthreads();

  // ---- phase 3a: gram (pass 1) -> deg -> dinv ----
#pragma unroll
  for (int ih = 0; ih < 2; ++ih) {
    int n0 = 32 * wid + 16 * ih;
    f32x4 g2[16] = {};
#pragma unroll
    for (int ks = 0; ks < 4; ++ks) {
      int k0 = ks * 32;
      bf16x8 af = lfragB(bufB, n0, k0, lane);
#pragma unroll
      for (int jt = 0; jt < 16; ++jt)
        g2[jt] = mfma(af, lfragB(bufB, 16 * jt, k0, lane), g2[jt]);
    }
#pragma unroll
    for (int r = 0; r < 4; ++r) {
      int i = n0 + 4 * hi + r;
      float sqi = lsq[i];
      bool mi = i < na;
      float rs = 0.f;
#pragma unroll
      for (int jt = 0; jt < 16; ++jt) {
        int j = 16 * jt + il;
        if (mi && j < na && i != j)
          rs += __expf(-sqrtf(fmaxf(sqi + lsq[j] - 2.f * g2[jt][r], D2_FLOOR)));
      }
      rs += __shfl_xor(rs, 1); rs += __shfl_xor(rs, 2);
      rs += __shfl_xor(rs, 4); rs += __shfl_xor(rs, 8);
      if (il == 0) dinvl[i] = mi ? 1.f / sqrtf(rs + EPS_F) : 0.f;
    }
  }
  __syncthreads();

  // ---- phase 3b: gram (recompute) -> llearn (f32) + L_cheb -> global Lb ----
  const float* lapb = lap + (size_t)b * cN * cN;
  float* llb = llearn + (size_t)b * cN * cN;
  bf16* lbb = Lb + (size_t)b * cN * cN;
#pragma unroll
  for (int ih = 0; ih < 2; ++ih) {
    int n0 = 32 * wid + 16 * ih;
    f32x4 g2[16] = {};
#pragma unroll
    for (int ks = 0; ks < 4; ++ks) {
      int k0 = ks * 32;
      bf16x8 af = lfragB(bufB, n0, k0, lane);
#pragma unroll
      for (int jt = 0; jt < 16; ++jt)
        g2[jt] = mfma(af, lfragB(bufB, 16 * jt, k0, lane), g2[jt]);
    }
#pragma unroll
    for (int r = 0; r < 4; ++r) {
      int i = n0 + 4 * hi + r;
      float sqi = lsq[i];
      bool mi = i < na;
      float di = dinvl[i];
      float mif = mi ? 1.f : 0.f;
#pragma unroll
      for (int jt = 0; jt < 16; ++jt) {
        int j = 16 * jt + il;
        float w = 0.f;
        if (mi && j < na && i != j)
          w = __expf(-sqrtf(fmaxf(sqi + lsq[j] - 2.f * g2[jt][r], D2_FLOOR)));
        float v = -di * w * dinvl[j];
        if (i == j && mi) v += 1.f;
        llb[(size_t)i * cN + j] = v;
        float mjf = (j < na) ? 1.f : 0.f;
        lbb[(size_t)i * cN + j] = (bf16)(v + lapb[(size_t)i * cN + j] * mif * mjf);
      }
    }
  }

  // ---- out accumulation + cheb chain ----
  f32x4 oacc[2][16] = {};  // [nt][ot]: rows i = 32wid+16nt+4hi+r, cols o = 16ot+il

#define SLICE(Bsrc, kst)                                                         \
  {                                                                              \
    const char* sb_ = (Bsrc);                                                    \
    _Pragma("unroll")                                                            \
    for (int ftp = 0; ftp < 4; ++ftp) {                                          \
      bf16x8 av[2];                                                              \
      _Pragma("unroll")                                                          \
      for (int nt = 0; nt < 2; ++nt) {                                           \
        int i_ = wid * 32 + nt * 16 + il;                                        \
        _Pragma("unroll")                                                        \
        for (int j = 0; j < 8; ++j) {                                            \
          int f_ = 32 * ftp + 8 * hi + j;                                        \
          av[nt][j] = *(const bf16*)(sb_ + f_ * 512 + ((2 * i_) ^ (j << 4)));    \
        }                                                                        \
      }                                                                          \
      _Pragma("unroll")                                                          \
      for (int ot = 0; ot < 16; ++ot) {                                          \
        bf16x8 bb = gfrag(Wt + (size_t)(16 * ot) * 512, 512, lane,               \
                          (kst) * 128 + 32 * ftp);                               \
        oacc[0][ot] = mfma(av[0], bb, oacc[0][ot]);                              \
        oacc[1][ot] = mfma(av[1], bb, oacc[1][ot]);                              \
      }                                                                          \
    }                                                                            \
  }

  SLICE(bufA, 0);           // x0 slice (overlaps 3b store latency)
  __syncthreads();          // drains vmcnt(0): Lb visible to whole block (same XCD)

  cheb_pass(lbb, bufA, nullptr, bufB, wid, lane, false);   // x1 -> bufB
  SLICE(bufB, 1);
  __syncthreads();
  cheb_pass(lbb, bufB, bufA, bufA, wid, lane, true);       // x2 -> bufA (pp=x0)
  SLICE(bufA, 2);
  __syncthreads();
  cheb_pass(lbb, bufA, bufB, bufB, wid, lane, true);       // x3 -> bufB (pp=x1)
  SLICE(bufB, 3);
#undef SLICE

  // ---- epilogue: bias + mask + relu ----
#pragma unroll
  for (int ot = 0; ot < 16; ++ot) {
    int o = 16 * ot + il;
    float bo = bias[o];
#pragma unroll
    for (int nt = 0; nt < 2; ++nt) {
#pragma unroll
      for (int r = 0; r < 4; ++r) {
        int n = wid * 32 + nt * 16 + 4 * hi + r;
        float m = (n < na) ? 1.f : 0.f;
        out[((size_t)b * cN + n) * cO + o] = fmaxf((oacc[nt][ot][r] + bo) * m, 0.f);
      }
    }
  }
}

// ---------------- launcher ----------------
extern "C" void kernel_launch(void* const* d_in, const int* in_sizes, int n_in,
                              void* d_out, int out_size, void* d_ws, size_t ws_size,
                              hipStream_t stream) {
  const float* x    = (const float*)d_in[0];
  const float* lap  = (const float*)d_in[1];
  const int*   na   = (const int*)d_in[2];
  const float* M_L  = (const float*)d_in[3];
  const float* wgt  = (const float*)d_in[4];
  const float* bias = (const float*)d_in[5];

  float* out    = (float*)d_out;
  float* llearn = out + (size_t)BN * cO;

  char* ws = (char*)d_ws;
  bf16* Lb = (bf16*)(ws + OFF_LB);
  bf16* Wt = (bf16*)(ws + OFF_WT);
  bf16* MT = (bf16*)(ws + OFF_MT);

  k_wt<<<dim3(576), 256, 0, stream>>>(wgt, M_L, Wt, MT);
  k_mega<<<dim3(cB), 512, 0, stream>>>(x, lap, na, MT, Wt, bias, Lb, out, llearn);
}